// Round 9
// baseline (494.316 us; speedup 1.0000x reference)
//
#include <hip/hip_runtime.h>
#include <hip/hip_bf16.h>
#include <math.h>

// B=4096 queries, D=256, K=65536 centroids (f32).
// Round 9 (this session): A/B matrix r5/r7/r8 (three cf paths, identical 165-169us,
// MfmaUtil pinned 38%) exonerates cf; invariant = qf LDS stream. Accounting: per
// kt-step/CU wall 1547 cyc; MFMA demand 512/SIMD; qf LDS 64KiB = 771 cyc @ measured
// 85 B/cyc -- qf BW + latency on every MFMA edge, unhideable at reg-capped 4
// waves/SIMD. Fix: wave tile cm=2 x qn=2 (r4's proven fragments) inside r7's
// 1024-thr/shared-As0/XCD-strip frame: qf traffic halves (32KiB/kt-step, 256-385
// cyc), cf doubles but L2-resident (242 cyc) -> MFMA pipe (512) becomes binding.
// acc 64 AGPR + arch ~56 = 120 <= 128 keeps 4 waves/SIMD. dm contract: grp =
// kc*256 + ct*16 + cslot*2 + cm, q-half = qh*64 (bijective). Tail untouched.
// Predict: scan 85-110us, MfmaUtil 55-75%; if ~165 unchanged -> latency/convoy
// theory wins, next round = setprio + pmin fusion.

#define DDIM 256
#define QTILE 128
#define STSZ 8192      // centroids per strip (8 kc strips; 16 ct x 512c)
#define QCAP 48        // candidate groups per query
#define F16_MINN 6.103515625e-5f

typedef __attribute__((ext_vector_type(8))) _Float16 half8;
typedef __attribute__((ext_vector_type(4))) _Float16 half4;
typedef __attribute__((ext_vector_type(4))) float f32x4;
typedef __attribute__((ext_vector_type(16))) float f32x16;

__device__ __forceinline__ void gl_lds16(const void* g, void* l) {
  __builtin_amdgcn_global_load_lds((const __attribute__((address_space(1))) void*)g,
                                   (__attribute__((address_space(3))) void*)l, 16, 0, 0);
}

// exact order-preserving float -> uint key (finite floats; matches f32 <)
__device__ __forceinline__ unsigned fkey(float d) {
  unsigned ud = __float_as_uint(d);
  return ud ^ (((int)ud < 0) ? 0xFFFFFFFFu : 0x80000000u);
}

// ---------------- ctl init: [32]=cmax_sq bits ----------------
__global__ void initctl_kernel(unsigned* __restrict__ ctl) {
  if (threadIdx.x < 64) ctl[threadIdx.x] = 0u;
}

// ---------------- centroid split + c_sq fused (one wave = one 256-elem row) --------
__global__ __launch_bounds__(256) void splitc_kernel(const float* __restrict__ in,
                                                     _Float16* __restrict__ o0,
                                                     float* __restrict__ c_sq) {
  int i = blockIdx.x * 256 + threadIdx.x;   // 4-elem chunk id; wave = one row
  int lane = (int)threadIdx.x & 63;
  float4 v = ((const float4*)in)[i];
  float vv[4] = {v.x, v.y, v.z, v.w};
  half4 h0;
#pragma unroll
  for (int e = 0; e < 4; ++e)
    h0[e] = (fabsf(vv[e]) < F16_MINN) ? (_Float16)0.f : (_Float16)vv[e];
  *(half4*)(o0 + (size_t)i * 4) = h0;
  float s = fmaf(v.x, v.x, fmaf(v.y, v.y, fmaf(v.z, v.z, v.w * v.w)));
#pragma unroll
  for (int off = 32; off > 0; off >>= 1) s += __shfl_down(s, off, 64);
  if (lane == 0) c_sq[i >> 6] = s;
}

// ---------------- x split: hi part only ----------------
__global__ __launch_bounds__(256) void splitx_kernel(const float* __restrict__ in,
                                                     _Float16* __restrict__ o0, int n4) {
  int i = blockIdx.x * 256 + threadIdx.x;
  if (i >= n4) return;
  float4 v = ((const float4*)in)[i];
  float vv[4] = {v.x, v.y, v.z, v.w};
  half4 h0;
#pragma unroll
  for (int e = 0; e < 4; ++e)
    h0[e] = (fabsf(vv[e]) < F16_MINN) ? (_Float16)0.f : (_Float16)vv[e];
  *(half4*)(o0 + (size_t)i * 4) = h0;
}

// ---------------- cmax: 2-stage max of c_sq, one atomic per block (64 total) --------
__global__ __launch_bounds__(256) void cmax_kernel(const float* __restrict__ c_sq,
                                                   unsigned* __restrict__ ctl) {
  __shared__ float red[4];
  int t = blockIdx.x * 256 + (int)threadIdx.x;
  float4 v = ((const float4*)c_sq)[t];
  float m = fmaxf(fmaxf(v.x, v.y), fmaxf(v.z, v.w));
#pragma unroll
  for (int off = 32; off > 0; off >>= 1) m = fmaxf(m, __shfl_down(m, off, 64));
  int lane = (int)threadIdx.x & 63, w = (int)threadIdx.x >> 6;
  if (lane == 0) red[w] = m;
  __syncthreads();
  if (threadIdx.x == 0) {
    m = fmaxf(fmaxf(red[0], red[1]), fmaxf(red[2], red[3]));
    atomicMax(&ctl[32], __float_as_uint(m));
  }
}

// ---------------- scan: 32x32x16 f16 MFMA, 1024-thr block, cm=2 x qn=2 waves ----
// Wave (cslot=w>>1, qh=w&1) owns 64c x 64q: 2 dm groups x one q-half per ct.
// A (centroids): lane l -> row l&31, k = (l>>5)*8 + e  (+kt*16)
// B (queries):   lane l -> col l&31, same k mapping
// C/D: col = lane&31 (query), row = (r&3) + 8*(r>>2) + 4*(lane>>5) (centroid).
// kc = blockIdx.x (fast): linear%8 = kc = XCD id -> each XCD owns ONE 4MB c0 strip.
__global__ __launch_bounds__(1024) void scan_kernel(
    const _Float16* __restrict__ x0, const _Float16* __restrict__ c0,
    const float* __restrict__ c_sq, float* __restrict__ dm) {
  __shared__ __align__(16) _Float16 As0[32768];   // 64 KiB: [s=kt*2+hi][q(128)][8]

  const int kc = blockIdx.x, qb = blockIdx.y;     // kc fast -> XCD-aligned strips
  const int tid = (int)threadIdx.x;
  const int lane = tid & 63, w = tid >> 6;        // w = 0..15
  const int lo = lane & 31, hi = lane >> 5;
  const int cslot = w >> 1, qh = w & 1;
  const int qrow0 = qb * QTILE;

  // stage x tile: 4096 16B chunks; chunk u = s*128+q holds x0[qrow0+q][s*8 .. s*8+7]
#pragma unroll
  for (int i = 0; i < 4; ++i) {
    int u = i * 1024 + tid;
    int q = u & 127, s = u >> 7;
    gl_lds16(x0 + (size_t)(qrow0 + q) * DDIM + s * 8, As0 + (size_t)u * 8);
  }
  __syncthreads();   // only barrier

  for (int ct = 0; ct < STSZ / 512; ++ct) {
    const int cbase = kc * STSZ + ct * 512 + cslot * 64;   // wave's 64-c slice
    f32x16 acc[2][2];                                       // [cm][qn]
#pragma unroll
    for (int cm = 0; cm < 2; ++cm)
#pragma unroll
      for (int qn = 0; qn < 2; ++qn) acc[cm][qn] = (f32x16)0.0f;

#pragma unroll 4
    for (int kt = 0; kt < 16; ++kt) {
      half8 cf[2];
#pragma unroll
      for (int cm = 0; cm < 2; ++cm)
        cf[cm] = *(const half8*)(c0 + (size_t)(cbase + cm * 32 + lo) * DDIM + kt * 16 + hi * 8);
      half8 qf[2];
#pragma unroll
      for (int qn = 0; qn < 2; ++qn)
        qf[qn] = *(const half8*)(As0 + (size_t)(((kt * 2 + hi) * QTILE) + qh * 64 + qn * 32 + lo) * 8);
#pragma unroll
      for (int cm = 0; cm < 2; ++cm)
#pragma unroll
        for (int qn = 0; qn < 2; ++qn)
          acc[cm][qn] = __builtin_amdgcn_mfma_f32_32x32x16_f16(cf[cm], qf[qn], acc[cm][qn], 0, 0, 0);
    }

    // epilogue: d = cs - 2*dot; min over 32 centroids (16 in-lane rows + hi xor)
#pragma unroll
    for (int cm = 0; cm < 2; ++cm) {
      f32x4 csv[4];
#pragma unroll
      for (int g = 0; g < 4; ++g)
        csv[g] = *(const f32x4*)(c_sq + cbase + cm * 32 + g * 8 + hi * 4);
      const int grp = kc * (STSZ / 32) + ct * 16 + cslot * 2 + cm;
      float* dmg = dm + (size_t)grp * 4096 + qrow0 + qh * 64;
#pragma unroll
      for (int qn = 0; qn < 2; ++qn) {
        float mq = INFINITY;
#pragma unroll
        for (int r = 0; r < 16; ++r)
          mq = fminf(mq, fmaf(-2.0f, acc[cm][qn][r], csv[r >> 2][r & 3]));
        mq = fminf(mq, __shfl_xor(mq, 32, 64));
        if (hi == 0) dmg[qn * 32 + lo] = mq;          // 32 lanes, 128 B dense
      }
    }
  }
}

// ---------------- pmin: partial column-min of dm ----------------
__global__ __launch_bounds__(256) void pmin_kernel(const float* __restrict__ dm,
                                                   float* __restrict__ pm) {
  int qc = blockIdx.x & 15, gc = blockIdx.x >> 4;
  int q = qc * 256 + (int)threadIdx.x;
  float m = INFINITY;
  for (int g = gc * 128; g < gc * 128 + 128; ++g)
    m = fminf(m, dm[(size_t)g * 4096 + q]);
  pm[gc * 4096 + q] = m;
}

// ---------------- tq: per-query threshold + cnt zero ----------------
__global__ __launch_bounds__(256) void tq_kernel(const float* __restrict__ pm,
                                                 const float* __restrict__ x,
                                                 const unsigned* __restrict__ ctl,
                                                 float* __restrict__ T,
                                                 unsigned* __restrict__ cnt) {
  int q = blockIdx.x * 256 + (int)threadIdx.x;
  float M = INFINITY;
#pragma unroll
  for (int i = 0; i < 16; ++i) M = fminf(M, pm[i * 4096 + q]);
  float xsq = 0.f;
  const float4* xr = (const float4*)(x + (size_t)q * DDIM);
#pragma unroll 8
  for (int i = 0; i < 64; ++i) {
    float4 v = xr[i];
    xsq = fmaf(v.x, v.x, fmaf(v.y, v.y, fmaf(v.z, v.z, fmaf(v.w, v.w, xsq))));
  }
  float cmaxsq = __uint_as_float(ctl[32]);
  // rigorous 1-term f16 bound ~2^-9 ||x|| ||c||max; margin = 4x bound + 1.0 slack
  T[q] = M + 0.0078125f * sqrtf(xsq * cmaxsq) + 1.0f;
  cnt[q] = 0u;
}

// ---------------- emit: per-query candidate group lists (distributed atomics) --------
__global__ __launch_bounds__(256) void emit_kernel(const float* __restrict__ dm,
                                                   const float* __restrict__ T,
                                                   unsigned short* __restrict__ cand,
                                                   unsigned* __restrict__ cnt) {
  int qc = blockIdx.x & 15, gc = blockIdx.x >> 4;
  int q = qc * 256 + (int)threadIdx.x;
  float t = T[q];
  for (int g = gc * 128; g < gc * 128 + 128; ++g)
    if (dm[(size_t)g * 4096 + q] <= t) {
      unsigned slot = atomicAdd(&cnt[q], 1u);   // 4096 distinct counters, ~2 ops each
      if (slot < QCAP) cand[(size_t)q * QCAP + slot] = (unsigned short)g;
    }
}

// ---------------- rescore+final: wave per query, atomic-free ----------------
__global__ __launch_bounds__(256) void rescore_final_kernel(
    const unsigned short* __restrict__ cand, const unsigned* __restrict__ cnt,
    const float* __restrict__ x, const float* __restrict__ cent,
    const float* __restrict__ c_sq, float* __restrict__ out) {
  int q = blockIdx.x * 4 + ((int)threadIdx.x >> 6);
  int lane = (int)threadIdx.x & 63;
  unsigned n = cnt[q];
  unsigned long long best = 0xFFFFFFFFFFFFFFFFull;
  if (n >= 1 && n <= QCAP) {
    int dh = (lane & 1) * 128;
    const float4* xr = (const float4*)(x + (size_t)q * DDIM + dh);
    for (unsigned sl = 0; sl < n; ++sl) {
      int g = (int)cand[(size_t)q * QCAP + sl];
      int c = g * 32 + (lane >> 1);
      const float4* cr = (const float4*)(cent + (size_t)c * DDIM + dh);
      float s = 0.f;
#pragma unroll
      for (int i = 0; i < 32; ++i) {
        float4 a = xr[i], bb = cr[i];
        s = fmaf(a.x, bb.x, fmaf(a.y, bb.y, fmaf(a.z, bb.z, fmaf(a.w, bb.w, s))));
      }
      s += __shfl_xor(s, 1, 64);
      float d = (lane & 1) ? INFINITY : fmaf(-2.0f, s, c_sq[c]);
      unsigned long long pkv = ((unsigned long long)fkey(d) << 32) | (unsigned)c;
      if (pkv < best) best = pkv;
    }
  } else {
    // safety net: exact argmin over all 65536 (overflow / empty; should never trigger)
    const float4* xr = (const float4*)(x + (size_t)q * DDIM);
    for (int c = lane; c < 65536; c += 64) {
      const float4* cr = (const float4*)(cent + (size_t)c * DDIM);
      float s = 0.f;
#pragma unroll 16
      for (int i = 0; i < 64; ++i) {
        float4 a = xr[i], bb = cr[i];
        s = fmaf(a.x, bb.x, fmaf(a.y, bb.y, fmaf(a.z, bb.z, fmaf(a.w, bb.w, s))));
      }
      float d = fmaf(-2.0f, s, c_sq[c]);
      unsigned long long pkv = ((unsigned long long)fkey(d) << 32) | (unsigned)c;
      if (pkv < best) best = pkv;
    }
  }
#pragma unroll
  for (int off = 1; off < 64; off <<= 1) {
    unsigned long long o = __shfl_xor(best, off, 64);
    if (o < best) best = o;
  }
  int idx = (int)(unsigned)(best & 0xFFFFFFFFu);
  float4 v = ((const float4*)cent)[(size_t)idx * 64 + lane];
  ((float4*)out)[(size_t)q * 64 + lane] = v;
  if (lane == 0) out[(size_t)4096 * DDIM + q] = (float)idx;
}

extern "C" void kernel_launch(void* const* d_in, const int* in_sizes, int n_in,
                              void* d_out, int out_size, void* d_ws, size_t ws_size,
                              hipStream_t stream) {
  const float* x    = (const float*)d_in[1];   // [4096,256]
  const float* cent = (const float*)d_in[2];   // [65536,256]
  float* out = (float*)d_out;
  char* ws = (char*)d_ws;

  const size_t OFF_C0   = 0;           // 33,554,432  f16 hi(centroids)
  const size_t OFF_X0   = 33554432;    //  2,097,152  f16 hi(x)
  const size_t OFF_CSQ  = 35651584;    //    262,144
  const size_t OFF_CTL  = 35913728;    //        256
  const size_t OFF_DM   = 35913984;    // 33,554,432  f32[2048][4096]
  const size_t OFF_PM   = 69468416;    //    262,144  f32[16][4096]
  const size_t OFF_T    = 69730560;    //     16,384
  const size_t OFF_CNT  = 69746944;    //     16,384  u32[4096]
  const size_t OFF_CAND = 69763328;    //    393,216  u16[4096][48]
  const size_t NEED     = 72089600;    // proven available since round 2
  if (ws_size < NEED) return;

  _Float16* c0 = (_Float16*)(ws + OFF_C0);
  _Float16* x0 = (_Float16*)(ws + OFF_X0);
  float* c_sq = (float*)(ws + OFF_CSQ);
  unsigned* ctl = (unsigned*)(ws + OFF_CTL);
  float* dm = (float*)(ws + OFF_DM);
  float* pm = (float*)(ws + OFF_PM);
  float* T  = (float*)(ws + OFF_T);
  unsigned* cnt = (unsigned*)(ws + OFF_CNT);
  unsigned short* cand = (unsigned short*)(ws + OFF_CAND);

  initctl_kernel<<<1, 64, 0, stream>>>(ctl);
  splitc_kernel<<<16384, 256, 0, stream>>>(cent, c0, c_sq);
  splitx_kernel<<<1024, 256, 0, stream>>>(x, x0, 4096 * 256 / 4);
  cmax_kernel<<<64, 256, 0, stream>>>(c_sq, ctl);
  scan_kernel<<<dim3(8, 32), 1024, 0, stream>>>(x0, c0, c_sq, dm);
  pmin_kernel<<<256, 256, 0, stream>>>(dm, pm);
  tq_kernel<<<16, 256, 0, stream>>>(pm, x, ctl, T, cnt);
  emit_kernel<<<256, 256, 0, stream>>>(dm, T, cand, cnt);
  rescore_final_kernel<<<1024, 256, 0, stream>>>(cand, cnt, x, cent, c_sq, out);
}

// Round 10
// 380.103 us; speedup vs baseline: 1.3005x; 1.3005x over previous
//
#include <hip/hip_runtime.h>
#include <hip/hip_bf16.h>
#include <math.h>

// B=4096 queries, D=256, K=65536 centroids (f32).
// Round 10 (this session): decisive A/B matrix: {r5,r7,r8} (qn=4, 1 cf dep/kt) =
// 165us/38%; {r4,r9} (2x2, 2 cf deps/kt) = 282-292us/20%. Wall tracks serialized
// mem-deps per MFMA batch, NOT qf bytes (r9 halved qf traffic and LOST) -- with
// ~12 spare VGPRs the compiler can't pipeline across kt; each kt pays latency then
// only 128 cyc MFMA. Lever: MFMA cyc per latency exposure. Switch to 16x16x32
// MFMA, wave = 32c (cm=2) x 128q (qn=8): 16 MFMA = 256 cyc/kt-step, acc stays
// 16 x f32x4 = 64 regs, kt-steps halve (8/ct). Fragments = prev-session r12's
// proven kernel (absmax 0) inside r7's 1024-thr/shared-As0/XCD-strip frame at
// 4 waves/SIMD (r12 was reg-starved at 2/SIMD -- that was its only flaw).
// qf LDS 128KB/CU/step = 1024-1541 cyc vs MFMA 1024 -> worst case 66% util.
// Predict: scan 85-120us, MfmaUtil 55-70%, VGPR ~64. Revert: FETCH>200MB or >=165us.

#define DDIM 256
#define QTILE 128
#define STSZ 8192      // centroids per strip (8 kc strips; 16 ct x 512c)
#define QCAP 48        // candidate groups per query
#define F16_MINN 6.103515625e-5f

typedef __attribute__((ext_vector_type(8))) _Float16 half8;
typedef __attribute__((ext_vector_type(4))) _Float16 half4;
typedef __attribute__((ext_vector_type(4))) float f32x4;

__device__ __forceinline__ void gl_lds16(const void* g, void* l) {
  __builtin_amdgcn_global_load_lds((const __attribute__((address_space(1))) void*)g,
                                   (__attribute__((address_space(3))) void*)l, 16, 0, 0);
}

// exact order-preserving float -> uint key (finite floats; matches f32 <)
__device__ __forceinline__ unsigned fkey(float d) {
  unsigned ud = __float_as_uint(d);
  return ud ^ (((int)ud < 0) ? 0xFFFFFFFFu : 0x80000000u);
}

// ---------------- ctl init: [32]=cmax_sq bits ----------------
__global__ void initctl_kernel(unsigned* __restrict__ ctl) {
  if (threadIdx.x < 64) ctl[threadIdx.x] = 0u;
}

// ---------------- centroid split + c_sq fused (one wave = one 256-elem row) --------
__global__ __launch_bounds__(256) void splitc_kernel(const float* __restrict__ in,
                                                     _Float16* __restrict__ o0,
                                                     float* __restrict__ c_sq) {
  int i = blockIdx.x * 256 + threadIdx.x;   // 4-elem chunk id; wave = one row
  int lane = (int)threadIdx.x & 63;
  float4 v = ((const float4*)in)[i];
  float vv[4] = {v.x, v.y, v.z, v.w};
  half4 h0;
#pragma unroll
  for (int e = 0; e < 4; ++e)
    h0[e] = (fabsf(vv[e]) < F16_MINN) ? (_Float16)0.f : (_Float16)vv[e];
  *(half4*)(o0 + (size_t)i * 4) = h0;
  float s = fmaf(v.x, v.x, fmaf(v.y, v.y, fmaf(v.z, v.z, v.w * v.w)));
#pragma unroll
  for (int off = 32; off > 0; off >>= 1) s += __shfl_down(s, off, 64);
  if (lane == 0) c_sq[i >> 6] = s;
}

// ---------------- x split: hi part only ----------------
__global__ __launch_bounds__(256) void splitx_kernel(const float* __restrict__ in,
                                                     _Float16* __restrict__ o0, int n4) {
  int i = blockIdx.x * 256 + threadIdx.x;
  if (i >= n4) return;
  float4 v = ((const float4*)in)[i];
  float vv[4] = {v.x, v.y, v.z, v.w};
  half4 h0;
#pragma unroll
  for (int e = 0; e < 4; ++e)
    h0[e] = (fabsf(vv[e]) < F16_MINN) ? (_Float16)0.f : (_Float16)vv[e];
  *(half4*)(o0 + (size_t)i * 4) = h0;
}

// ---------------- cmax: 2-stage max of c_sq, one atomic per block (64 total) --------
__global__ __launch_bounds__(256) void cmax_kernel(const float* __restrict__ c_sq,
                                                   unsigned* __restrict__ ctl) {
  __shared__ float red[4];
  int t = blockIdx.x * 256 + (int)threadIdx.x;
  float4 v = ((const float4*)c_sq)[t];
  float m = fmaxf(fmaxf(v.x, v.y), fmaxf(v.z, v.w));
#pragma unroll
  for (int off = 32; off > 0; off >>= 1) m = fmaxf(m, __shfl_down(m, off, 64));
  int lane = (int)threadIdx.x & 63, w = (int)threadIdx.x >> 6;
  if (lane == 0) red[w] = m;
  __syncthreads();
  if (threadIdx.x == 0) {
    m = fmaxf(fmaxf(red[0], red[1]), fmaxf(red[2], red[3]));
    atomicMax(&ctl[32], __float_as_uint(m));
  }
}

// ---------------- scan: 16x16x32 f16 MFMA, 1024-thr block, 16 waves share As0 ----
// Wave w owns c-slice [cbase, cbase+32) = one dm group per ct (cm=2 x 16c).
// A (centroids): lane l -> row l&15, k = (l>>4)*8 + e  (+kt*32)
// B (queries):   lane l -> col l&15, same k mapping
// C/D: col = lane&15 (query), row = (lane>>4)*4 + r  (centroid, within 16-tile).
// kc = blockIdx.x (fast): linear%8 = kc = XCD id -> each XCD owns ONE 4MB c0 strip.
__global__ __launch_bounds__(1024) void scan_kernel(
    const _Float16* __restrict__ x0, const _Float16* __restrict__ c0,
    const float* __restrict__ c_sq, float* __restrict__ dm) {
  __shared__ __align__(16) _Float16 As0[32768];   // 64 KiB: [s=kt*4+quad][q(128)][8]

  const int kc = blockIdx.x, qb = blockIdx.y;     // kc fast -> XCD-aligned strips
  const int tid = (int)threadIdx.x;
  const int lane = tid & 63, w = tid >> 6;        // w = 0..15
  const int col = lane & 15, quad = lane >> 4;
  const int qrow0 = qb * QTILE;

  // stage x tile: 4096 16B chunks; chunk u = s*128+q holds x0[qrow0+q][s*8 .. s*8+7]
#pragma unroll
  for (int i = 0; i < 4; ++i) {
    int u = i * 1024 + tid;
    int q = u & 127, s = u >> 7;
    gl_lds16(x0 + (size_t)(qrow0 + q) * DDIM + s * 8, As0 + (size_t)u * 8);
  }
  __syncthreads();   // only barrier

  for (int ct = 0; ct < STSZ / 512; ++ct) {
    const int cbase = kc * STSZ + ct * 512 + w * 32;   // wave-private 32-c group
    f32x4 acc[2][8];                                    // [cm][qn]
#pragma unroll
    for (int cm = 0; cm < 2; ++cm)
#pragma unroll
      for (int qn = 0; qn < 8; ++qn) acc[cm][qn] = (f32x4)0.0f;

#pragma unroll 2
    for (int kt = 0; kt < 8; ++kt) {
      const int k0 = kt * 32;
      half8 cf[2];
#pragma unroll
      for (int cm = 0; cm < 2; ++cm)
        cf[cm] = *(const half8*)(c0 + (size_t)(cbase + cm * 16 + col) * DDIM + k0 + quad * 8);
#pragma unroll
      for (int qn = 0; qn < 8; ++qn) {
        half8 qf = *(const half8*)(As0 + (size_t)(((kt * 4 + quad) * QTILE) + qn * 16 + col) * 8);
#pragma unroll
        for (int cm = 0; cm < 2; ++cm)
          acc[cm][qn] = __builtin_amdgcn_mfma_f32_16x16x32_f16(cf[cm], qf, acc[cm][qn], 0, 0, 0);
      }
    }

    // epilogue: d = cs - 2*dot; min over 32 centroids (2 cm x 4 rg in-lane + quad xor)
    f32x4 csv[2];
#pragma unroll
    for (int cm = 0; cm < 2; ++cm)
      csv[cm] = *(const f32x4*)(c_sq + cbase + cm * 16 + quad * 4);
    const int grp = kc * (STSZ / 32) + ct * 16 + w;
    float* dmg = dm + (size_t)grp * 4096 + qrow0;
#pragma unroll
    for (int qn = 0; qn < 8; ++qn) {
      float mq = INFINITY;
#pragma unroll
      for (int cm = 0; cm < 2; ++cm)
#pragma unroll
        for (int rg = 0; rg < 4; ++rg)
          mq = fminf(mq, fmaf(-2.0f, acc[cm][qn][rg], csv[cm][rg]));
      mq = fminf(mq, __shfl_xor(mq, 16, 64));
      mq = fminf(mq, __shfl_xor(mq, 32, 64));
      if (quad == 0) dmg[qn * 16 + col] = mq;         // 16 lanes, 64 B dense
    }
  }
}

// ---------------- pmin: partial column-min of dm ----------------
__global__ __launch_bounds__(256) void pmin_kernel(const float* __restrict__ dm,
                                                   float* __restrict__ pm) {
  int qc = blockIdx.x & 15, gc = blockIdx.x >> 4;
  int q = qc * 256 + (int)threadIdx.x;
  float m = INFINITY;
  for (int g = gc * 128; g < gc * 128 + 128; ++g)
    m = fminf(m, dm[(size_t)g * 4096 + q]);
  pm[gc * 4096 + q] = m;
}

// ---------------- tq: per-query threshold + cnt zero ----------------
__global__ __launch_bounds__(256) void tq_kernel(const float* __restrict__ pm,
                                                 const float* __restrict__ x,
                                                 const unsigned* __restrict__ ctl,
                                                 float* __restrict__ T,
                                                 unsigned* __restrict__ cnt) {
  int q = blockIdx.x * 256 + (int)threadIdx.x;
  float M = INFINITY;
#pragma unroll
  for (int i = 0; i < 16; ++i) M = fminf(M, pm[i * 4096 + q]);
  float xsq = 0.f;
  const float4* xr = (const float4*)(x + (size_t)q * DDIM);
#pragma unroll 8
  for (int i = 0; i < 64; ++i) {
    float4 v = xr[i];
    xsq = fmaf(v.x, v.x, fmaf(v.y, v.y, fmaf(v.z, v.z, fmaf(v.w, v.w, xsq))));
  }
  float cmaxsq = __uint_as_float(ctl[32]);
  // rigorous 1-term f16 bound ~2^-9 ||x|| ||c||max; margin = 4x bound + 1.0 slack
  T[q] = M + 0.0078125f * sqrtf(xsq * cmaxsq) + 1.0f;
  cnt[q] = 0u;
}

// ---------------- emit: per-query candidate group lists (distributed atomics) --------
__global__ __launch_bounds__(256) void emit_kernel(const float* __restrict__ dm,
                                                   const float* __restrict__ T,
                                                   unsigned short* __restrict__ cand,
                                                   unsigned* __restrict__ cnt) {
  int qc = blockIdx.x & 15, gc = blockIdx.x >> 4;
  int q = qc * 256 + (int)threadIdx.x;
  float t = T[q];
  for (int g = gc * 128; g < gc * 128 + 128; ++g)
    if (dm[(size_t)g * 4096 + q] <= t) {
      unsigned slot = atomicAdd(&cnt[q], 1u);   // 4096 distinct counters, ~2 ops each
      if (slot < QCAP) cand[(size_t)q * QCAP + slot] = (unsigned short)g;
    }
}

// ---------------- rescore+final: wave per query, atomic-free ----------------
__global__ __launch_bounds__(256) void rescore_final_kernel(
    const unsigned short* __restrict__ cand, const unsigned* __restrict__ cnt,
    const float* __restrict__ x, const float* __restrict__ cent,
    const float* __restrict__ c_sq, float* __restrict__ out) {
  int q = blockIdx.x * 4 + ((int)threadIdx.x >> 6);
  int lane = (int)threadIdx.x & 63;
  unsigned n = cnt[q];
  unsigned long long best = 0xFFFFFFFFFFFFFFFFull;
  if (n >= 1 && n <= QCAP) {
    int dh = (lane & 1) * 128;
    const float4* xr = (const float4*)(x + (size_t)q * DDIM + dh);
    for (unsigned sl = 0; sl < n; ++sl) {
      int g = (int)cand[(size_t)q * QCAP + sl];
      int c = g * 32 + (lane >> 1);
      const float4* cr = (const float4*)(cent + (size_t)c * DDIM + dh);
      float s = 0.f;
#pragma unroll
      for (int i = 0; i < 32; ++i) {
        float4 a = xr[i], bb = cr[i];
        s = fmaf(a.x, bb.x, fmaf(a.y, bb.y, fmaf(a.z, bb.z, fmaf(a.w, bb.w, s))));
      }
      s += __shfl_xor(s, 1, 64);
      float d = (lane & 1) ? INFINITY : fmaf(-2.0f, s, c_sq[c]);
      unsigned long long pkv = ((unsigned long long)fkey(d) << 32) | (unsigned)c;
      if (pkv < best) best = pkv;
    }
  } else {
    // safety net: exact argmin over all 65536 (overflow / empty; should never trigger)
    const float4* xr = (const float4*)(x + (size_t)q * DDIM);
    for (int c = lane; c < 65536; c += 64) {
      const float4* cr = (const float4*)(cent + (size_t)c * DDIM);
      float s = 0.f;
#pragma unroll 16
      for (int i = 0; i < 64; ++i) {
        float4 a = xr[i], bb = cr[i];
        s = fmaf(a.x, bb.x, fmaf(a.y, bb.y, fmaf(a.z, bb.z, fmaf(a.w, bb.w, s))));
      }
      float d = fmaf(-2.0f, s, c_sq[c]);
      unsigned long long pkv = ((unsigned long long)fkey(d) << 32) | (unsigned)c;
      if (pkv < best) best = pkv;
    }
  }
#pragma unroll
  for (int off = 1; off < 64; off <<= 1) {
    unsigned long long o = __shfl_xor(best, off, 64);
    if (o < best) best = o;
  }
  int idx = (int)(unsigned)(best & 0xFFFFFFFFu);
  float4 v = ((const float4*)cent)[(size_t)idx * 64 + lane];
  ((float4*)out)[(size_t)q * 64 + lane] = v;
  if (lane == 0) out[(size_t)4096 * DDIM + q] = (float)idx;
}

extern "C" void kernel_launch(void* const* d_in, const int* in_sizes, int n_in,
                              void* d_out, int out_size, void* d_ws, size_t ws_size,
                              hipStream_t stream) {
  const float* x    = (const float*)d_in[1];   // [4096,256]
  const float* cent = (const float*)d_in[2];   // [65536,256]
  float* out = (float*)d_out;
  char* ws = (char*)d_ws;

  const size_t OFF_C0   = 0;           // 33,554,432  f16 hi(centroids)
  const size_t OFF_X0   = 33554432;    //  2,097,152  f16 hi(x)
  const size_t OFF_CSQ  = 35651584;    //    262,144
  const size_t OFF_CTL  = 35913728;    //        256
  const size_t OFF_DM   = 35913984;    // 33,554,432  f32[2048][4096]
  const size_t OFF_PM   = 69468416;    //    262,144  f32[16][4096]
  const size_t OFF_T    = 69730560;    //     16,384
  const size_t OFF_CNT  = 69746944;    //     16,384  u32[4096]
  const size_t OFF_CAND = 69763328;    //    393,216  u16[4096][48]
  const size_t NEED     = 72089600;    // proven available since round 2
  if (ws_size < NEED) return;

  _Float16* c0 = (_Float16*)(ws + OFF_C0);
  _Float16* x0 = (_Float16*)(ws + OFF_X0);
  float* c_sq = (float*)(ws + OFF_CSQ);
  unsigned* ctl = (unsigned*)(ws + OFF_CTL);
  float* dm = (float*)(ws + OFF_DM);
  float* pm = (float*)(ws + OFF_PM);
  float* T  = (float*)(ws + OFF_T);
  unsigned* cnt = (unsigned*)(ws + OFF_CNT);
  unsigned short* cand = (unsigned short*)(ws + OFF_CAND);

  initctl_kernel<<<1, 64, 0, stream>>>(ctl);
  splitc_kernel<<<16384, 256, 0, stream>>>(cent, c0, c_sq);
  splitx_kernel<<<1024, 256, 0, stream>>>(x, x0, 4096 * 256 / 4);
  cmax_kernel<<<64, 256, 0, stream>>>(c_sq, ctl);
  scan_kernel<<<dim3(8, 32), 1024, 0, stream>>>(x0, c0, c_sq, dm);
  pmin_kernel<<<256, 256, 0, stream>>>(dm, pm);
  tq_kernel<<<16, 256, 0, stream>>>(pm, x, ctl, T, cnt);
  emit_kernel<<<256, 256, 0, stream>>>(dm, T, cand, cnt);
  rescore_final_kernel<<<1024, 256, 0, stream>>>(cand, cnt, x, cent, c_sq, out);
}

// Round 11
// 355.231 us; speedup vs baseline: 1.3915x; 1.0700x over previous
//
#include <hip/hip_runtime.h>
#include <hip/hip_bf16.h>
#include <math.h>

// B=4096 queries, D=256, K=65536 centroids (f32).
// Round 11 (this session): TAIL round. Scan plateaued at 158us/38% across 6
// variants (per-kt wall ~2960cyc vs 1020 MFMA + ~1540 LDS-demand = structural
// latency residue). Total-scan = 222us tail, untouched this session. Cuts:
// (1) pmin fused into scan via LDS running-min pmred[16][128] (8KB, bank-clean)
//     -> pm[8][4096] written by scan; pmin kernel + 32MB re-read deleted.
// (2) rescore: block-per-query (grid 4096), 4 waves split candidates, LDS
//     ull-min cross-wave reduce; fallback also 4x. Same min-over-set semantics.
// (3) initctl folded into splitx block 0 (cmax later in stream order).
// Scan inner loop = r10 VERBATIM. Predict total 380 -> 325-345us; scan ~158
// (VGPR 56, LDS 73728). Revert: absmax!=0 -> rescore; scan>170 -> pm fusion.

#define DDIM 256
#define QTILE 128
#define STSZ 8192      // centroids per strip (8 kc strips; 16 ct x 512c)
#define QCAP 48        // candidate groups per query
#define F16_MINN 6.103515625e-5f

typedef __attribute__((ext_vector_type(8))) _Float16 half8;
typedef __attribute__((ext_vector_type(4))) _Float16 half4;
typedef __attribute__((ext_vector_type(4))) float f32x4;

__device__ __forceinline__ void gl_lds16(const void* g, void* l) {
  __builtin_amdgcn_global_load_lds((const __attribute__((address_space(1))) void*)g,
                                   (__attribute__((address_space(3))) void*)l, 16, 0, 0);
}

// exact order-preserving float -> uint key (finite floats; matches f32 <)
__device__ __forceinline__ unsigned fkey(float d) {
  unsigned ud = __float_as_uint(d);
  return ud ^ (((int)ud < 0) ? 0xFFFFFFFFu : 0x80000000u);
}

// ---------------- centroid split + c_sq fused (one wave = one 256-elem row) --------
__global__ __launch_bounds__(256) void splitc_kernel(const float* __restrict__ in,
                                                     _Float16* __restrict__ o0,
                                                     float* __restrict__ c_sq) {
  int i = blockIdx.x * 256 + threadIdx.x;   // 4-elem chunk id; wave = one row
  int lane = (int)threadIdx.x & 63;
  float4 v = ((const float4*)in)[i];
  float vv[4] = {v.x, v.y, v.z, v.w};
  half4 h0;
#pragma unroll
  for (int e = 0; e < 4; ++e)
    h0[e] = (fabsf(vv[e]) < F16_MINN) ? (_Float16)0.f : (_Float16)vv[e];
  *(half4*)(o0 + (size_t)i * 4) = h0;
  float s = fmaf(v.x, v.x, fmaf(v.y, v.y, fmaf(v.z, v.z, v.w * v.w)));
#pragma unroll
  for (int off = 32; off > 0; off >>= 1) s += __shfl_down(s, off, 64);
  if (lane == 0) c_sq[i >> 6] = s;
}

// ---------------- x split (+ ctl zero by block 0) ----------------
__global__ __launch_bounds__(256) void splitx_kernel(const float* __restrict__ in,
                                                     _Float16* __restrict__ o0, int n4,
                                                     unsigned* __restrict__ ctl) {
  if (blockIdx.x == 0 && threadIdx.x < 64) ctl[threadIdx.x] = 0u;
  int i = blockIdx.x * 256 + threadIdx.x;
  if (i >= n4) return;
  float4 v = ((const float4*)in)[i];
  float vv[4] = {v.x, v.y, v.z, v.w};
  half4 h0;
#pragma unroll
  for (int e = 0; e < 4; ++e)
    h0[e] = (fabsf(vv[e]) < F16_MINN) ? (_Float16)0.f : (_Float16)vv[e];
  *(half4*)(o0 + (size_t)i * 4) = h0;
}

// ---------------- cmax: 2-stage max of c_sq, one atomic per block (64 total) --------
__global__ __launch_bounds__(256) void cmax_kernel(const float* __restrict__ c_sq,
                                                   unsigned* __restrict__ ctl) {
  __shared__ float red[4];
  int t = blockIdx.x * 256 + (int)threadIdx.x;
  float4 v = ((const float4*)c_sq)[t];
  float m = fmaxf(fmaxf(v.x, v.y), fmaxf(v.z, v.w));
#pragma unroll
  for (int off = 32; off > 0; off >>= 1) m = fmaxf(m, __shfl_down(m, off, 64));
  int lane = (int)threadIdx.x & 63, w = (int)threadIdx.x >> 6;
  if (lane == 0) red[w] = m;
  __syncthreads();
  if (threadIdx.x == 0) {
    m = fmaxf(fmaxf(red[0], red[1]), fmaxf(red[2], red[3]));
    atomicMax(&ctl[32], __float_as_uint(m));
  }
}

// ---------------- scan: 16x16x32 f16 MFMA, 1024-thr block + fused pm ----
// Wave w owns c-slice [cbase, cbase+32) = one dm group per ct (cm=2 x 16c).
// A (centroids): lane l -> row l&15, k = (l>>4)*8 + e  (+kt*32)
// B (queries):   lane l -> col l&15, same k mapping
// C/D: col = lane&15 (query), row = (lane>>4)*4 + r  (centroid, within 16-tile).
// kc = blockIdx.x (fast): linear%8 = kc = XCD id -> each XCD owns ONE 4MB c0 strip.
// pmred[w][q]: per-wave running min over its 16 ct groups; reduced to pm[kc][q].
__global__ __launch_bounds__(1024) void scan_kernel(
    const _Float16* __restrict__ x0, const _Float16* __restrict__ c0,
    const float* __restrict__ c_sq, float* __restrict__ dm,
    float* __restrict__ pm) {
  __shared__ __align__(16) _Float16 As0[32768];   // 64 KiB: [s=kt*4+quad][q(128)][8]
  __shared__ float pmred[2048];                   // 8 KiB: [w(16)][q(128)]

  const int kc = blockIdx.x, qb = blockIdx.y;     // kc fast -> XCD-aligned strips
  const int tid = (int)threadIdx.x;
  const int lane = tid & 63, w = tid >> 6;        // w = 0..15
  const int col = lane & 15, quad = lane >> 4;
  const int qrow0 = qb * QTILE;

  pmred[tid] = INFINITY;
  pmred[tid + 1024] = INFINITY;

  // stage x tile: 4096 16B chunks; chunk u = s*128+q holds x0[qrow0+q][s*8 .. s*8+7]
#pragma unroll
  for (int i = 0; i < 4; ++i) {
    int u = i * 1024 + tid;
    int q = u & 127, s = u >> 7;
    gl_lds16(x0 + (size_t)(qrow0 + q) * DDIM + s * 8, As0 + (size_t)u * 8);
  }
  __syncthreads();   // As0 + pmred ready

  for (int ct = 0; ct < STSZ / 512; ++ct) {
    const int cbase = kc * STSZ + ct * 512 + w * 32;   // wave-private 32-c group
    f32x4 acc[2][8];                                    // [cm][qn]
#pragma unroll
    for (int cm = 0; cm < 2; ++cm)
#pragma unroll
      for (int qn = 0; qn < 8; ++qn) acc[cm][qn] = (f32x4)0.0f;

#pragma unroll 2
    for (int kt = 0; kt < 8; ++kt) {
      const int k0 = kt * 32;
      half8 cf[2];
#pragma unroll
      for (int cm = 0; cm < 2; ++cm)
        cf[cm] = *(const half8*)(c0 + (size_t)(cbase + cm * 16 + col) * DDIM + k0 + quad * 8);
#pragma unroll
      for (int qn = 0; qn < 8; ++qn) {
        half8 qf = *(const half8*)(As0 + (size_t)(((kt * 4 + quad) * QTILE) + qn * 16 + col) * 8);
#pragma unroll
        for (int cm = 0; cm < 2; ++cm)
          acc[cm][qn] = __builtin_amdgcn_mfma_f32_16x16x32_f16(cf[cm], qf, acc[cm][qn], 0, 0, 0);
      }
    }

    // epilogue: d = cs - 2*dot; min over 32 centroids (2 cm x 4 rg in-lane + quad xor)
    f32x4 csv[2];
#pragma unroll
    for (int cm = 0; cm < 2; ++cm)
      csv[cm] = *(const f32x4*)(c_sq + cbase + cm * 16 + quad * 4);
    const int grp = kc * (STSZ / 32) + ct * 16 + w;
    float* dmg = dm + (size_t)grp * 4096 + qrow0;
#pragma unroll
    for (int qn = 0; qn < 8; ++qn) {
      float mq = INFINITY;
#pragma unroll
      for (int cm = 0; cm < 2; ++cm)
#pragma unroll
        for (int rg = 0; rg < 4; ++rg)
          mq = fminf(mq, fmaf(-2.0f, acc[cm][qn][rg], csv[cm][rg]));
      mq = fminf(mq, __shfl_xor(mq, 16, 64));
      mq = fminf(mq, __shfl_xor(mq, 32, 64));
      if (quad == 0) {
        dmg[qn * 16 + col] = mq;                      // 16 lanes, 64 B dense
        const int pi = w * 128 + qn * 16 + col;       // banks: col -> 16 distinct
        pmred[pi] = fminf(pmred[pi], mq);
      }
    }
  }

  __syncthreads();
  if (tid < 128) {       // waves 0-1: column-min over 16 wave rows -> pm[kc][q]
    float m = INFINITY;
#pragma unroll
    for (int i = 0; i < 16; ++i) m = fminf(m, pmred[i * 128 + tid]);
    pm[(size_t)kc * 4096 + qrow0 + tid] = m;
  }
}

// ---------------- tq: per-query threshold + cnt zero ----------------
__global__ __launch_bounds__(256) void tq_kernel(const float* __restrict__ pm,
                                                 const float* __restrict__ x,
                                                 const unsigned* __restrict__ ctl,
                                                 float* __restrict__ T,
                                                 unsigned* __restrict__ cnt) {
  int q = blockIdx.x * 256 + (int)threadIdx.x;
  float M = INFINITY;
#pragma unroll
  for (int i = 0; i < 8; ++i) M = fminf(M, pm[i * 4096 + q]);
  float xsq = 0.f;
  const float4* xr = (const float4*)(x + (size_t)q * DDIM);
#pragma unroll 8
  for (int i = 0; i < 64; ++i) {
    float4 v = xr[i];
    xsq = fmaf(v.x, v.x, fmaf(v.y, v.y, fmaf(v.z, v.z, fmaf(v.w, v.w, xsq))));
  }
  float cmaxsq = __uint_as_float(ctl[32]);
  // rigorous 1-term f16 bound ~2^-9 ||x|| ||c||max; margin = 4x bound + 1.0 slack
  T[q] = M + 0.0078125f * sqrtf(xsq * cmaxsq) + 1.0f;
  cnt[q] = 0u;
}

// ---------------- emit: per-query candidate group lists (distributed atomics) --------
__global__ __launch_bounds__(256) void emit_kernel(const float* __restrict__ dm,
                                                   const float* __restrict__ T,
                                                   unsigned short* __restrict__ cand,
                                                   unsigned* __restrict__ cnt) {
  int qc = blockIdx.x & 15, gc = blockIdx.x >> 4;
  int q = qc * 256 + (int)threadIdx.x;
  float t = T[q];
  for (int g = gc * 128; g < gc * 128 + 128; ++g)
    if (dm[(size_t)g * 4096 + q] <= t) {
      unsigned slot = atomicAdd(&cnt[q], 1u);   // 4096 distinct counters, ~2 ops each
      if (slot < QCAP) cand[(size_t)q * QCAP + slot] = (unsigned short)g;
    }
}

// ---------------- rescore+final: BLOCK per query, 4 waves split candidates ----------
__global__ __launch_bounds__(256) void rescore_final_kernel(
    const unsigned short* __restrict__ cand, const unsigned* __restrict__ cnt,
    const float* __restrict__ x, const float* __restrict__ cent,
    const float* __restrict__ c_sq, float* __restrict__ out) {
  __shared__ unsigned long long red[4];
  const int q = blockIdx.x;
  const int w = (int)threadIdx.x >> 6, lane = (int)threadIdx.x & 63;
  const unsigned n = cnt[q];
  unsigned long long best = 0xFFFFFFFFFFFFFFFFull;
  if (n >= 1 && n <= QCAP) {
    int dh = (lane & 1) * 128;
    const float4* xr = (const float4*)(x + (size_t)q * DDIM + dh);
    for (unsigned sl = (unsigned)w; sl < n; sl += 4) {
      int g = (int)cand[(size_t)q * QCAP + sl];
      int c = g * 32 + (lane >> 1);
      const float4* cr = (const float4*)(cent + (size_t)c * DDIM + dh);
      float s = 0.f;
#pragma unroll
      for (int i = 0; i < 32; ++i) {
        float4 a = xr[i], bb = cr[i];
        s = fmaf(a.x, bb.x, fmaf(a.y, bb.y, fmaf(a.z, bb.z, fmaf(a.w, bb.w, s))));
      }
      s += __shfl_xor(s, 1, 64);
      float d = (lane & 1) ? INFINITY : fmaf(-2.0f, s, c_sq[c]);
      unsigned long long pkv = ((unsigned long long)fkey(d) << 32) | (unsigned)c;
      if (pkv < best) best = pkv;
    }
  } else {
    // safety net: exact argmin over all 65536 (overflow / empty; should never trigger)
    const float4* xr = (const float4*)(x + (size_t)q * DDIM);
    for (int c = (w << 6) + lane; c < 65536; c += 256) {
      const float4* cr = (const float4*)(cent + (size_t)c * DDIM);
      float s = 0.f;
#pragma unroll 16
      for (int i = 0; i < 64; ++i) {
        float4 a = xr[i], bb = cr[i];
        s = fmaf(a.x, bb.x, fmaf(a.y, bb.y, fmaf(a.z, bb.z, fmaf(a.w, bb.w, s))));
      }
      float d = fmaf(-2.0f, s, c_sq[c]);
      unsigned long long pkv = ((unsigned long long)fkey(d) << 32) | (unsigned)c;
      if (pkv < best) best = pkv;
    }
  }
#pragma unroll
  for (int off = 1; off < 64; off <<= 1) {
    unsigned long long o = __shfl_xor(best, off, 64);
    if (o < best) best = o;
  }
  if (lane == 0) red[w] = best;
  __syncthreads();
  if (w == 0) {
    unsigned long long b = red[lane & 3];
#pragma unroll
    for (int off = 1; off < 4; off <<= 1) {
      unsigned long long o = __shfl_xor(b, off, 64);
      if (o < b) b = o;
    }
    int idx = (int)(unsigned)(b & 0xFFFFFFFFu);
    float4 v = ((const float4*)cent)[(size_t)idx * 64 + lane];
    ((float4*)out)[(size_t)q * 64 + lane] = v;
    if (lane == 0) out[(size_t)4096 * DDIM + q] = (float)idx;
  }
}

extern "C" void kernel_launch(void* const* d_in, const int* in_sizes, int n_in,
                              void* d_out, int out_size, void* d_ws, size_t ws_size,
                              hipStream_t stream) {
  const float* x    = (const float*)d_in[1];   // [4096,256]
  const float* cent = (const float*)d_in[2];   // [65536,256]
  float* out = (float*)d_out;
  char* ws = (char*)d_ws;

  const size_t OFF_C0   = 0;           // 33,554,432  f16 hi(centroids)
  const size_t OFF_X0   = 33554432;    //  2,097,152  f16 hi(x)
  const size_t OFF_CSQ  = 35651584;    //    262,144
  const size_t OFF_CTL  = 35913728;    //        256
  const size_t OFF_DM   = 35913984;    // 33,554,432  f32[2048][4096]
  const size_t OFF_PM   = 69468416;    //    262,144  f32[8][4096] used
  const size_t OFF_T    = 69730560;    //     16,384
  const size_t OFF_CNT  = 69746944;    //     16,384  u32[4096]
  const size_t OFF_CAND = 69763328;    //    393,216  u16[4096][48]
  const size_t NEED     = 72089600;    // proven available since round 2
  if (ws_size < NEED) return;

  _Float16* c0 = (_Float16*)(ws + OFF_C0);
  _Float16* x0 = (_Float16*)(ws + OFF_X0);
  float* c_sq = (float*)(ws + OFF_CSQ);
  unsigned* ctl = (unsigned*)(ws + OFF_CTL);
  float* dm = (float*)(ws + OFF_DM);
  float* pm = (float*)(ws + OFF_PM);
  float* T  = (float*)(ws + OFF_T);
  unsigned* cnt = (unsigned*)(ws + OFF_CNT);
  unsigned short* cand = (unsigned short*)(ws + OFF_CAND);

  splitc_kernel<<<16384, 256, 0, stream>>>(cent, c0, c_sq);
  splitx_kernel<<<1024, 256, 0, stream>>>(x, x0, 4096 * 256 / 4, ctl);
  cmax_kernel<<<64, 256, 0, stream>>>(c_sq, ctl);
  scan_kernel<<<dim3(8, 32), 1024, 0, stream>>>(x0, c0, c_sq, dm, pm);
  tq_kernel<<<16, 256, 0, stream>>>(pm, x, ctl, T, cnt);
  emit_kernel<<<256, 256, 0, stream>>>(dm, T, cand, cnt);
  rescore_final_kernel<<<4096, 256, 0, stream>>>(cand, cnt, x, cent, c_sq, out);
}

// Round 12
// 326.056 us; speedup vs baseline: 1.5160x; 1.0895x over previous
//
#include <hip/hip_runtime.h>
#include <hip/hip_bf16.h>
#include <math.h>

// B=4096 queries, D=256, K=65536 centroids (f32).
// Round 12 (this session): tail consolidation. r11 proved pm-fusion free (scan
// 157us unchanged) and cut 25us; remaining tail ~198us >> BW floor (~60us) ->
// launch gaps + small-kernel latency phases across 7 serialized dispatches.
// Merge tq+emit+rescore into ONE finish kernel (block = 16 queries, grid 256,
// 512 thr): ph1 T (xsq 32thr/q + pm min), ph2 emit (coalesced 64B dm segments,
// LDS atomics, order-invariant => same semantics), ph3 exact rescore (wave per
// 2 queries, same pkv tie-break, fallback kept), fused writeback. 7->5 kernels.
// Scan/splitc/splitx/cmax untouched. Predict total 355 -> 315-335us; revert if
// absmax!=0 (finish) or total>355 (r11).

#define DDIM 256
#define QTILE 128
#define STSZ 8192      // centroids per strip (8 kc strips; 16 ct x 512c)
#define QCAP 48        // candidate groups per query
#define F16_MINN 6.103515625e-5f

typedef __attribute__((ext_vector_type(8))) _Float16 half8;
typedef __attribute__((ext_vector_type(4))) _Float16 half4;
typedef __attribute__((ext_vector_type(4))) float f32x4;

__device__ __forceinline__ void gl_lds16(const void* g, void* l) {
  __builtin_amdgcn_global_load_lds((const __attribute__((address_space(1))) void*)g,
                                   (__attribute__((address_space(3))) void*)l, 16, 0, 0);
}

// exact order-preserving float -> uint key (finite floats; matches f32 <)
__device__ __forceinline__ unsigned fkey(float d) {
  unsigned ud = __float_as_uint(d);
  return ud ^ (((int)ud < 0) ? 0xFFFFFFFFu : 0x80000000u);
}

// ---------------- centroid split + c_sq fused (one wave = one 256-elem row) --------
__global__ __launch_bounds__(256) void splitc_kernel(const float* __restrict__ in,
                                                     _Float16* __restrict__ o0,
                                                     float* __restrict__ c_sq) {
  int i = blockIdx.x * 256 + threadIdx.x;   // 4-elem chunk id; wave = one row
  int lane = (int)threadIdx.x & 63;
  float4 v = ((const float4*)in)[i];
  float vv[4] = {v.x, v.y, v.z, v.w};
  half4 h0;
#pragma unroll
  for (int e = 0; e < 4; ++e)
    h0[e] = (fabsf(vv[e]) < F16_MINN) ? (_Float16)0.f : (_Float16)vv[e];
  *(half4*)(o0 + (size_t)i * 4) = h0;
  float s = fmaf(v.x, v.x, fmaf(v.y, v.y, fmaf(v.z, v.z, v.w * v.w)));
#pragma unroll
  for (int off = 32; off > 0; off >>= 1) s += __shfl_down(s, off, 64);
  if (lane == 0) c_sq[i >> 6] = s;
}

// ---------------- x split (+ ctl zero by block 0) ----------------
__global__ __launch_bounds__(256) void splitx_kernel(const float* __restrict__ in,
                                                     _Float16* __restrict__ o0, int n4,
                                                     unsigned* __restrict__ ctl) {
  if (blockIdx.x == 0 && threadIdx.x < 64) ctl[threadIdx.x] = 0u;
  int i = blockIdx.x * 256 + threadIdx.x;
  if (i >= n4) return;
  float4 v = ((const float4*)in)[i];
  float vv[4] = {v.x, v.y, v.z, v.w};
  half4 h0;
#pragma unroll
  for (int e = 0; e < 4; ++e)
    h0[e] = (fabsf(vv[e]) < F16_MINN) ? (_Float16)0.f : (_Float16)vv[e];
  *(half4*)(o0 + (size_t)i * 4) = h0;
}

// ---------------- cmax: 2-stage max of c_sq, one atomic per block (64 total) --------
__global__ __launch_bounds__(256) void cmax_kernel(const float* __restrict__ c_sq,
                                                   unsigned* __restrict__ ctl) {
  __shared__ float red[4];
  int t = blockIdx.x * 256 + (int)threadIdx.x;
  float4 v = ((const float4*)c_sq)[t];
  float m = fmaxf(fmaxf(v.x, v.y), fmaxf(v.z, v.w));
#pragma unroll
  for (int off = 32; off > 0; off >>= 1) m = fmaxf(m, __shfl_down(m, off, 64));
  int lane = (int)threadIdx.x & 63, w = (int)threadIdx.x >> 6;
  if (lane == 0) red[w] = m;
  __syncthreads();
  if (threadIdx.x == 0) {
    m = fmaxf(fmaxf(red[0], red[1]), fmaxf(red[2], red[3]));
    atomicMax(&ctl[32], __float_as_uint(m));
  }
}

// ---------------- scan: 16x16x32 f16 MFMA, 1024-thr block + fused pm ----
// Wave w owns c-slice [cbase, cbase+32) = one dm group per ct (cm=2 x 16c).
// A (centroids): lane l -> row l&15, k = (l>>4)*8 + e  (+kt*32)
// B (queries):   lane l -> col l&15, same k mapping
// C/D: col = lane&15 (query), row = (lane>>4)*4 + r  (centroid, within 16-tile).
// kc = blockIdx.x (fast): linear%8 = kc = XCD id -> each XCD owns ONE 4MB c0 strip.
// pmred[w][q]: per-wave running min over its 16 ct groups; reduced to pm[kc][q].
__global__ __launch_bounds__(1024) void scan_kernel(
    const _Float16* __restrict__ x0, const _Float16* __restrict__ c0,
    const float* __restrict__ c_sq, float* __restrict__ dm,
    float* __restrict__ pm) {
  __shared__ __align__(16) _Float16 As0[32768];   // 64 KiB: [s=kt*4+quad][q(128)][8]
  __shared__ float pmred[2048];                   // 8 KiB: [w(16)][q(128)]

  const int kc = blockIdx.x, qb = blockIdx.y;     // kc fast -> XCD-aligned strips
  const int tid = (int)threadIdx.x;
  const int lane = tid & 63, w = tid >> 6;        // w = 0..15
  const int col = lane & 15, quad = lane >> 4;
  const int qrow0 = qb * QTILE;

  pmred[tid] = INFINITY;
  pmred[tid + 1024] = INFINITY;

  // stage x tile: 4096 16B chunks; chunk u = s*128+q holds x0[qrow0+q][s*8 .. s*8+7]
#pragma unroll
  for (int i = 0; i < 4; ++i) {
    int u = i * 1024 + tid;
    int q = u & 127, s = u >> 7;
    gl_lds16(x0 + (size_t)(qrow0 + q) * DDIM + s * 8, As0 + (size_t)u * 8);
  }
  __syncthreads();   // As0 + pmred ready

  for (int ct = 0; ct < STSZ / 512; ++ct) {
    const int cbase = kc * STSZ + ct * 512 + w * 32;   // wave-private 32-c group
    f32x4 acc[2][8];                                    // [cm][qn]
#pragma unroll
    for (int cm = 0; cm < 2; ++cm)
#pragma unroll
      for (int qn = 0; qn < 8; ++qn) acc[cm][qn] = (f32x4)0.0f;

#pragma unroll 2
    for (int kt = 0; kt < 8; ++kt) {
      const int k0 = kt * 32;
      half8 cf[2];
#pragma unroll
      for (int cm = 0; cm < 2; ++cm)
        cf[cm] = *(const half8*)(c0 + (size_t)(cbase + cm * 16 + col) * DDIM + k0 + quad * 8);
#pragma unroll
      for (int qn = 0; qn < 8; ++qn) {
        half8 qf = *(const half8*)(As0 + (size_t)(((kt * 4 + quad) * QTILE) + qn * 16 + col) * 8);
#pragma unroll
        for (int cm = 0; cm < 2; ++cm)
          acc[cm][qn] = __builtin_amdgcn_mfma_f32_16x16x32_f16(cf[cm], qf, acc[cm][qn], 0, 0, 0);
      }
    }

    // epilogue: d = cs - 2*dot; min over 32 centroids (2 cm x 4 rg in-lane + quad xor)
    f32x4 csv[2];
#pragma unroll
    for (int cm = 0; cm < 2; ++cm)
      csv[cm] = *(const f32x4*)(c_sq + cbase + cm * 16 + quad * 4);
    const int grp = kc * (STSZ / 32) + ct * 16 + w;
    float* dmg = dm + (size_t)grp * 4096 + qrow0;
#pragma unroll
    for (int qn = 0; qn < 8; ++qn) {
      float mq = INFINITY;
#pragma unroll
      for (int cm = 0; cm < 2; ++cm)
#pragma unroll
        for (int rg = 0; rg < 4; ++rg)
          mq = fminf(mq, fmaf(-2.0f, acc[cm][qn][rg], csv[cm][rg]));
      mq = fminf(mq, __shfl_xor(mq, 16, 64));
      mq = fminf(mq, __shfl_xor(mq, 32, 64));
      if (quad == 0) {
        dmg[qn * 16 + col] = mq;                      // 16 lanes, 64 B dense
        const int pi = w * 128 + qn * 16 + col;       // banks: col -> 16 distinct
        pmred[pi] = fminf(pmred[pi], mq);
      }
    }
  }

  __syncthreads();
  if (tid < 128) {       // column-min over 16 wave rows -> pm[kc][q]
    float m = INFINITY;
#pragma unroll
    for (int i = 0; i < 16; ++i) m = fminf(m, pmred[i * 128 + tid]);
    pm[(size_t)kc * 4096 + qrow0 + tid] = m;
  }
}

// ---------------- finish: fused tq + emit + rescore + writeback ----------------
// Block = 16 queries (grid 256, 512 thr = 8 waves).
// ph1: T[qi] = min_kc pm + f16 error margin (same formula as before).
// ph2: emit -- thread t reads dm[g*4096 + q0 + (t&15)], g = (t>>4) + 32i (64B
//      coalesced segments); hits -> LDS atomic slot in candL[qi]. Order differs
//      from global version but min-over-set is order-invariant.
// ph3: wave w rescores queries {w, w+8}: exact f32 dot (2 lanes/centroid),
//      pkv=(fkey(d)<<32)|c min-reduce; fallback full-scan if overflow.
__global__ __launch_bounds__(512) void finish_kernel(
    const float* __restrict__ pm, const float* __restrict__ x,
    const unsigned* __restrict__ ctl, const float* __restrict__ dm,
    const float* __restrict__ cent, const float* __restrict__ c_sq,
    float* __restrict__ out) {
  __shared__ float Tl[16];
  __shared__ unsigned cnt16[16];
  __shared__ unsigned short candL[16][QCAP];
  __shared__ float xred[16][33];
  __shared__ unsigned long long bestL[16];

  const int t = (int)threadIdx.x;
  const int w = t >> 6, lane = t & 63;
  const int q0 = (int)blockIdx.x * 16;

  // ph1a: xsq partials (32 threads per query, 8 floats each)
  {
    int qi = t >> 5, ch = t & 31;
    const float4* xr = (const float4*)(x + (size_t)(q0 + qi) * DDIM + ch * 8);
    float s = 0.f;
#pragma unroll
    for (int j = 0; j < 2; ++j) {
      float4 v = xr[j];
      s = fmaf(v.x, v.x, fmaf(v.y, v.y, fmaf(v.z, v.z, fmaf(v.w, v.w, s))));
    }
    xred[qi][ch] = s;
    if (t < 16) cnt16[t] = 0u;
  }
  __syncthreads();
  // ph1b: T
  if (t < 16) {
    float xsq = 0.f;
#pragma unroll
    for (int i = 0; i < 32; ++i) xsq += xred[t][i];
    float M = INFINITY;
#pragma unroll
    for (int i = 0; i < 8; ++i) M = fminf(M, pm[i * 4096 + q0 + t]);
    float cmaxsq = __uint_as_float(ctl[32]);
    // rigorous 1-term f16 bound ~2^-9 ||x|| ||c||max; margin = 4x bound + 1.0 slack
    Tl[t] = M + 0.0078125f * sqrtf(xsq * cmaxsq) + 1.0f;
  }
  __syncthreads();

  // ph2: emit
  {
    const int qi = t & 15, g0 = t >> 4;
    const float Tq = Tl[qi];
#pragma unroll 4
    for (int i = 0; i < 64; ++i) {
      int g = g0 + i * 32;
      float v = dm[(size_t)g * 4096 + q0 + qi];
      if (v <= Tq) {
        unsigned slot = atomicAdd(&cnt16[qi], 1u);
        if (slot < QCAP) candL[qi][slot] = (unsigned short)g;
      }
    }
  }
  __syncthreads();

  // ph3: rescore -- wave w handles queries w and w+8
#pragma unroll
  for (int k = 0; k < 2; ++k) {
    const int qi = w + k * 8;
    const unsigned n = cnt16[qi];
    unsigned long long bq = 0xFFFFFFFFFFFFFFFFull;
    if (n >= 1 && n <= QCAP) {
      int dh = (lane & 1) * 128;
      const float4* xr = (const float4*)(x + (size_t)(q0 + qi) * DDIM + dh);
      for (unsigned sl = 0; sl < n; ++sl) {
        int g = (int)candL[qi][sl];
        int c = g * 32 + (lane >> 1);
        const float4* cr = (const float4*)(cent + (size_t)c * DDIM + dh);
        float s = 0.f;
#pragma unroll
        for (int i = 0; i < 32; ++i) {
          float4 a = xr[i], bb = cr[i];
          s = fmaf(a.x, bb.x, fmaf(a.y, bb.y, fmaf(a.z, bb.z, fmaf(a.w, bb.w, s))));
        }
        s += __shfl_xor(s, 1, 64);
        float d = (lane & 1) ? INFINITY : fmaf(-2.0f, s, c_sq[c]);
        unsigned long long pkv = ((unsigned long long)fkey(d) << 32) | (unsigned)c;
        if (pkv < bq) bq = pkv;
      }
    } else {
      // safety net: exact argmin over all 65536 (overflow; should never trigger)
      const float4* xr = (const float4*)(x + (size_t)(q0 + qi) * DDIM);
      for (int c = lane; c < 65536; c += 64) {
        const float4* cr = (const float4*)(cent + (size_t)c * DDIM);
        float s = 0.f;
#pragma unroll 16
        for (int i = 0; i < 64; ++i) {
          float4 a = xr[i], bb = cr[i];
          s = fmaf(a.x, bb.x, fmaf(a.y, bb.y, fmaf(a.z, bb.z, fmaf(a.w, bb.w, s))));
        }
        float d = fmaf(-2.0f, s, c_sq[c]);
        unsigned long long pkv = ((unsigned long long)fkey(d) << 32) | (unsigned)c;
        if (pkv < bq) bq = pkv;
      }
    }
#pragma unroll
    for (int off = 1; off < 64; off <<= 1) {
      unsigned long long o = __shfl_xor(bq, off, 64);
      if (o < bq) bq = o;
    }
    if (lane == 0) bestL[qi] = bq;
  }
  __syncthreads();

  // writeback: 32 threads per query (2 float4 each = 256 dims), + code scalar
  {
    int qi = t >> 5, part = t & 31;
    int idx = (int)(unsigned)(bestL[qi] & 0xFFFFFFFFu);
    const float4* cr = (const float4*)(cent + (size_t)idx * DDIM);
    float4* orow = (float4*)(out + (size_t)(q0 + qi) * DDIM);
#pragma unroll
    for (int j = 0; j < 2; ++j) orow[part * 2 + j] = cr[part * 2 + j];
    if (part == 0) out[(size_t)4096 * DDIM + q0 + qi] = (float)idx;
  }
}

extern "C" void kernel_launch(void* const* d_in, const int* in_sizes, int n_in,
                              void* d_out, int out_size, void* d_ws, size_t ws_size,
                              hipStream_t stream) {
  const float* x    = (const float*)d_in[1];   // [4096,256]
  const float* cent = (const float*)d_in[2];   // [65536,256]
  float* out = (float*)d_out;
  char* ws = (char*)d_ws;

  const size_t OFF_C0   = 0;           // 33,554,432  f16 hi(centroids)
  const size_t OFF_X0   = 33554432;    //  2,097,152  f16 hi(x)
  const size_t OFF_CSQ  = 35651584;    //    262,144
  const size_t OFF_CTL  = 35913728;    //        256
  const size_t OFF_DM   = 35913984;    // 33,554,432  f32[2048][4096]
  const size_t OFF_PM   = 69468416;    //    262,144  f32[8][4096] used
  const size_t NEED     = 72089600;    // proven available since round 2
  if (ws_size < NEED) return;

  _Float16* c0 = (_Float16*)(ws + OFF_C0);
  _Float16* x0 = (_Float16*)(ws + OFF_X0);
  float* c_sq = (float*)(ws + OFF_CSQ);
  unsigned* ctl = (unsigned*)(ws + OFF_CTL);
  float* dm = (float*)(ws + OFF_DM);
  float* pm = (float*)(ws + OFF_PM);

  splitc_kernel<<<16384, 256, 0, stream>>>(cent, c0, c_sq);
  splitx_kernel<<<1024, 256, 0, stream>>>(x, x0, 4096 * 256 / 4, ctl);
  cmax_kernel<<<64, 256, 0, stream>>>(c_sq, ctl);
  scan_kernel<<<dim3(8, 32), 1024, 0, stream>>>(x0, c0, c_sq, dm, pm);
  finish_kernel<<<256, 512, 0, stream>>>(pm, x, ctl, dm, cent, c_sq, out);
}